// Round 1
// baseline (485.514 us; speedup 1.0000x reference)
//
#include <hip/hip_runtime.h>
#include <math.h>

#define BATCH 256
#define M 128        // txt rows
#define NIMG 127     // valid img cols
#define NP 128       // padded img cols
#define D 1024
#define DK 32        // k-tile
#define ITERS 50
#define XTP 132      // padded LDS stride for staging tiles (breaks pow2 conflicts)

__launch_bounds__(256, 1)
__global__ void ot_loss_kernel(const float* __restrict__ xg,   // (256,128,1024)
                               const float* __restrict__ yg,   // (256,128,1024)
                               const int* __restrict__ xnum,   // (256,128)
                               const int* __restrict__ ynum,   // (256,128)
                               float* __restrict__ out)
{
    __shared__ float sxT[DK][XTP];     // xT[k][i]
    __shared__ float syT[DK][XTP];     // yT[k][j]
    __shared__ float partA[16 * 128];  // colsum partials [ti][j]
    __shared__ float partB[16 * 128];  // rowsum partials [tj][i]
    __shared__ float red4[4 * 256];    // norm partials
    __shared__ float sdelta[NP];
    __shared__ float ssigma[M];
    __shared__ float sxmask[M];        // 0 or 1e4
    __shared__ float symask[NP];
    __shared__ float sinvx[M];
    __shared__ float sinvy[NP];
    __shared__ float sxl, syl;
    __shared__ float swsum[4];
    __shared__ unsigned int swcnt[8];

    const int b  = blockIdx.x;
    const int t  = threadIdx.x;
    const int ti = t >> 4;        // 0..15 (i-group)
    const int tj = t & 15;        // 0..15 (j-group)
    const int i0 = ti * 8;
    const int j0 = tj * 8;

    const float* xb = xg + (size_t)b * M * D;
    const float* yb = yg + ((size_t)b * 128 + 1) * D;   // object_vec[:,1:]

    // ---------------- setup: pads, masks, lengths, sigma0 ----------------
    bool tpad = true, ipad = true;
    if (t < M) {
        tpad = (xnum[b * M + t] == 0);
        sxmask[t] = tpad ? 1e4f : 0.0f;
        if (t < NIMG) ipad = (ynum[b * 128 + t + 1] == 0);
        else          ipad = true;
        symask[t] = ipad ? 1e4f : 0.0f;
    }
    unsigned long long bx = __ballot(t < M    && !tpad);
    unsigned long long by = __ballot(t < NIMG && !ipad);
    const int wave = t >> 6;
    if ((t & 63) == 0) {
        swcnt[wave]     = (unsigned)__popcll(bx);
        swcnt[4 + wave] = (unsigned)__popcll(by);
    }
    __syncthreads();
    if (t == 0) {
        sxl = (float)(swcnt[0] + swcnt[1] + swcnt[2] + swcnt[3]);
        syl = (float)(swcnt[4] + swcnt[5] + swcnt[6] + swcnt[7]);
    }
    __syncthreads();
    if (t < M) ssigma[t] = tpad ? 0.0f : (1.0f / sxl);   // sigma0

    // ---------------- phase 1: dot products + row norms ----------------
    float acc[8][8];
#pragma unroll
    for (int ii = 0; ii < 8; ++ii)
#pragma unroll
        for (int jj = 0; jj < 8; ++jj) acc[ii][jj] = 0.0f;

    float sx[4] = {0.f, 0.f, 0.f, 0.f};
    float sy[4] = {0.f, 0.f, 0.f, 0.f};

    for (int kk = 0; kk < D; kk += DK) {
#pragma unroll
        for (int it = 0; it < 4; ++it) {
            const int idx = it * 256 + t;     // 0..1023
            const int row = idx >> 3;         // 0..127 (same rows every tile)
            const int c0  = (idx & 7) << 2;   // 0,4,...,28
            float4 vx = *(const float4*)(xb + (size_t)row * D + kk + c0);
            sx[it] = fmaf(vx.x, vx.x, sx[it]);
            sx[it] = fmaf(vx.y, vx.y, sx[it]);
            sx[it] = fmaf(vx.z, vx.z, sx[it]);
            sx[it] = fmaf(vx.w, vx.w, sx[it]);
            sxT[c0 + 0][row] = vx.x;
            sxT[c0 + 1][row] = vx.y;
            sxT[c0 + 2][row] = vx.z;
            sxT[c0 + 3][row] = vx.w;
            float4 vy;
            if (row < NIMG) vy = *(const float4*)(yb + (size_t)row * D + kk + c0);
            else            vy = make_float4(0.f, 0.f, 0.f, 0.f);
            sy[it] = fmaf(vy.x, vy.x, sy[it]);
            sy[it] = fmaf(vy.y, vy.y, sy[it]);
            sy[it] = fmaf(vy.z, vy.z, sy[it]);
            sy[it] = fmaf(vy.w, vy.w, sy[it]);
            syT[c0 + 0][row] = vy.x;
            syT[c0 + 1][row] = vy.y;
            syT[c0 + 2][row] = vy.z;
            syT[c0 + 3][row] = vy.w;
        }
        __syncthreads();
#pragma unroll 4
        for (int k = 0; k < DK; ++k) {
            float xv[8], yv[8];
#pragma unroll
            for (int u = 0; u < 8; ++u) xv[u] = sxT[k][i0 + u];
#pragma unroll
            for (int u = 0; u < 8; ++u) yv[u] = syT[k][j0 + u];
#pragma unroll
            for (int ii = 0; ii < 8; ++ii)
#pragma unroll
                for (int jj = 0; jj < 8; ++jj)
                    acc[ii][jj] = fmaf(xv[ii], yv[jj], acc[ii][jj]);
        }
        __syncthreads();
    }

    // ---- norm reductions: inv_norm = 1/max(sqrt(sumsq), 1e-5) ----
#pragma unroll
    for (int it = 0; it < 4; ++it) red4[it * 256 + t] = sx[it];
    __syncthreads();
    if (t < M) {
        const int base = (t >> 5) * 256 + (t & 31) * 8;
        float s = 0.f;
#pragma unroll
        for (int u = 0; u < 8; ++u) s += red4[base + u];
        sinvx[t] = 1.0f / fmaxf(sqrtf(s), 1e-5f);
    }
    __syncthreads();
#pragma unroll
    for (int it = 0; it < 4; ++it) red4[it * 256 + t] = sy[it];
    __syncthreads();
    if (t < NP) {
        const int base = (t >> 5) * 256 + (t & 31) * 8;
        float s = 0.f;
#pragma unroll
        for (int u = 0; u < 8; ++u) s += red4[base + u];
        sinvy[t] = 1.0f / fmaxf(sqrtf(s), 1e-5f);
    }
    __syncthreads();

    // ---- convert to A-tilde = masked exp(-2C); Q-tilde = A-tilde ----
    float ivx[8], ivy[8], xmf[8], ymf[8];
#pragma unroll
    for (int u = 0; u < 8; ++u) {
        ivx[u] = sinvx[i0 + u];
        xmf[u] = sxmask[i0 + u];
        ivy[u] = sinvy[j0 + u];
        ymf[u] = symask[j0 + u];
    }
    float qf[8][8];
#pragma unroll
    for (int ii = 0; ii < 8; ++ii)
#pragma unroll
        for (int jj = 0; jj < 8; ++jj) {
            float Cv = 1.0f - acc[ii][jj] * ivx[ii] * ivy[jj];
            bool masked = (xmf[ii] != 0.0f) || (ymf[jj] != 0.0f);
            float a = masked ? 0.0f : expf(-2.0f * Cv);   // beta = 0.5
            acc[ii][jj] = a;   // acc now holds A-tilde
            qf[ii][jj]  = a;   // Q0 = A (T0 = 1 on unmasked)
        }

    // ---------------- phase 2: 50 IPOT iterations ----------------
    float lp = 0.0f;
    for (int itn = 0; itn < ITERS; ++itn) {
        // colsum[j] = sum_i sigma[i] * Q[i][j]
        float sg[8];
#pragma unroll
        for (int u = 0; u < 8; ++u) sg[u] = ssigma[i0 + u];
        float cp[8] = {0.f,0.f,0.f,0.f,0.f,0.f,0.f,0.f};
#pragma unroll
        for (int ii = 0; ii < 8; ++ii)
#pragma unroll
            for (int jj = 0; jj < 8; ++jj)
                cp[jj] = fmaf(sg[ii], qf[ii][jj], cp[jj]);
#pragma unroll
        for (int u = 0; u < 8; ++u) partA[ti * 128 + j0 + u] = cp[u];
        __syncthreads();
        if (t < NP) {
            float s = 0.f;
#pragma unroll
            for (int r = 0; r < 16; ++r) s += partA[r * 128 + t];
            sdelta[t] = 1.0f / (syl * s + symask[t]);
        }
        __syncthreads();
        // rowsum[i] = sum_j delta[j] * Q[i][j]
        float dl[8];
#pragma unroll
        for (int u = 0; u < 8; ++u) dl[u] = sdelta[j0 + u];
        float rp[8] = {0.f,0.f,0.f,0.f,0.f,0.f,0.f,0.f};
#pragma unroll
        for (int ii = 0; ii < 8; ++ii)
#pragma unroll
            for (int jj = 0; jj < 8; ++jj)
                rp[ii] = fmaf(dl[jj], qf[ii][jj], rp[ii]);
#pragma unroll
        for (int u = 0; u < 8; ++u) partB[tj * 128 + i0 + u] = rp[u];
        __syncthreads();
        if (t < M) {
            float s = 0.f;
#pragma unroll
            for (int r = 0; r < 16; ++r) s += partB[r * 128 + t];
            ssigma[t] = 1.0f / (sxl * s + sxmask[t]);
        }
        __syncthreads();
        float sn[8];
#pragma unroll
        for (int u = 0; u < 8; ++u) sn[u] = ssigma[i0 + u];
        if (itn < ITERS - 1) {
#pragma unroll
            for (int ii = 0; ii < 8; ++ii)
#pragma unroll
                for (int jj = 0; jj < 8; ++jj)
                    qf[ii][jj] *= acc[ii][jj] * dl[jj] * sn[ii];
        } else {
            // loss = sum C * delta[j] * sigma[i] * Q[i][j]; C = -0.5*ln(A)
#pragma unroll
            for (int ii = 0; ii < 8; ++ii)
#pragma unroll
                for (int jj = 0; jj < 8; ++jj) {
                    float a = acc[ii][jj];
                    if (a > 0.0f) {
                        float Cv = -0.5f * logf(a);
                        lp = fmaf(Cv * dl[jj] * sn[ii], qf[ii][jj], lp);
                    }
                }
        }
    }

    // ---------------- block reduce + atomic accumulate ----------------
#pragma unroll
    for (int off = 32; off > 0; off >>= 1) lp += __shfl_down(lp, off);
    if ((t & 63) == 0) swsum[wave] = lp;
    __syncthreads();
    if (t == 0) {
        float total = swsum[0] + swsum[1] + swsum[2] + swsum[3];
        atomicAdd(out, 0.01f * total);
    }
}

extern "C" void kernel_launch(void* const* d_in, const int* in_sizes, int n_in,
                              void* d_out, int out_size, void* d_ws, size_t ws_size,
                              hipStream_t stream) {
    const float* x   = (const float*)d_in[0];
    const float* y   = (const float*)d_in[1];
    const int*   xn  = (const int*)d_in[2];
    const int*   yn  = (const int*)d_in[3];
    float* out = (float*)d_out;

    hipMemsetAsync(out, 0, (size_t)out_size * sizeof(float), stream);
    ot_loss_kernel<<<dim3(BATCH), dim3(256), 0, stream>>>(x, y, xn, yn, out);
}

// Round 3
// 385.252 us; speedup vs baseline: 1.2603x; 1.2603x over previous
//
#include <hip/hip_runtime.h>
#include <math.h>

#define BATCH 256
#define M 128        // txt rows
#define NIMG 127     // valid img cols
#define NP 128       // padded img cols
#define D 1024
#define BK 64        // k-tile
#define ITERS 50
#define LROW 72      // LDS row stride in bf16 elems (64 + 8 pad -> 144 B)

typedef __attribute__((ext_vector_type(8))) short bf16x8;
typedef __attribute__((ext_vector_type(4))) float floatx4;

// pack two floats to bf16x2 (RNE), bit-level (no __hip_bfloat162 needed)
static __device__ __forceinline__ unsigned pack_bf16x2(float a, float b) {
    unsigned ua = __builtin_bit_cast(unsigned, a);
    unsigned ub = __builtin_bit_cast(unsigned, b);
    ua += 0x7fffu + ((ua >> 16) & 1u);
    ub += 0x7fffu + ((ub >> 16) & 1u);
    return (ua >> 16) | (ub & 0xffff0000u);
}

// ---------------- K1: cosine-cost GEMM -> A = exp(-2C) masked ----------------
// One block per batch. 512 threads = 8 waves. MFMA 16x16x32 bf16.
// Wave w: tile-rows {(w&3)*32, +16}, tile-cols {(w>>2)*64 + 16*tc}.
__launch_bounds__(512, 1)
__global__ void gemm_a_kernel(const float* __restrict__ xg,   // (256,128,1024)
                              const float* __restrict__ yg,   // (256,128,1024)
                              const int* __restrict__ xnum,
                              const int* __restrict__ ynum,
                              float* __restrict__ Aout)       // (256,128,128)
{
    __shared__ __align__(16) short Xs[M * LROW];
    __shared__ __align__(16) short Ys[M * LROW];
    __shared__ __align__(16) float sinvx[M];
    __shared__ __align__(16) float sinvy[NP];
    __shared__ __align__(16) float sxmask[M];   // 1.0 if pad
    __shared__ __align__(16) float symask[NP];

    const int b    = blockIdx.x;
    const int t    = threadIdx.x;
    const int lane = t & 63;
    const int w    = t >> 6;

    const float* xb = xg + (size_t)b * M * D;
    const float* yb = yg + ((size_t)b * 128 + 1) * D;   // object_vec[:,1:]

    if (t < M)  sxmask[t] = (xnum[b * M + t] == 0) ? 1.0f : 0.0f;
    if (t < NP) symask[t] = (t < NIMG && ynum[b * 128 + t + 1] != 0) ? 0.0f : 1.0f;

    // staging assignment: thread covers rows r0, r0+32, r0+64, r0+96; 16 floats/row-chunk
    const int r0  = t >> 4;      // 0..31
    const int c16 = t & 15;      // float4 column within 64-wide k-tile

    floatx4 acc[2][4];
#pragma unroll
    for (int a = 0; a < 2; ++a)
#pragma unroll
        for (int c = 0; c < 4; ++c) acc[a][c] = (floatx4)0.0f;

    float ssx[4] = {0.f, 0.f, 0.f, 0.f};
    float ssy[4] = {0.f, 0.f, 0.f, 0.f};

    const int mbase = (w & 3) * 32;
    const int nbase = (w >> 2) * 64;
    const int col   = lane & 15;
    const int quad  = lane >> 4;

    for (int kk = 0; kk < D; kk += BK) {
        __syncthreads();   // previous iter's frag reads done before restage
#pragma unroll
        for (int it = 0; it < 4; ++it) {
            const int r = r0 + it * 32;
            float4 vx = *(const float4*)(xb + (size_t)r * D + kk + c16 * 4);
            ssx[it] = fmaf(vx.x, vx.x, fmaf(vx.y, vx.y, fmaf(vx.z, vx.z, fmaf(vx.w, vx.w, ssx[it]))));
            uint2 px;
            px.x = pack_bf16x2(vx.x, vx.y);
            px.y = pack_bf16x2(vx.z, vx.w);
            *(uint2*)(&Xs[r * LROW + c16 * 4]) = px;

            float4 vy = make_float4(0.f, 0.f, 0.f, 0.f);
            if (r < NIMG) vy = *(const float4*)(yb + (size_t)r * D + kk + c16 * 4);
            ssy[it] = fmaf(vy.x, vy.x, fmaf(vy.y, vy.y, fmaf(vy.z, vy.z, fmaf(vy.w, vy.w, ssy[it]))));
            uint2 py;
            py.x = pack_bf16x2(vy.x, vy.y);
            py.y = pack_bf16x2(vy.z, vy.w);
            *(uint2*)(&Ys[r * LROW + c16 * 4]) = py;
        }
        __syncthreads();

#pragma unroll
        for (int ks = 0; ks < 2; ++ks) {
            const int koff = ks * 32 + quad * 8;
            bf16x8 af[2], bfr[4];
#pragma unroll
            for (int tr = 0; tr < 2; ++tr)
                af[tr] = *(const bf16x8*)(&Xs[(mbase + tr * 16 + col) * LROW + koff]);
#pragma unroll
            for (int tc = 0; tc < 4; ++tc)
                bfr[tc] = *(const bf16x8*)(&Ys[(nbase + tc * 16 + col) * LROW + koff]);
#pragma unroll
            for (int tr = 0; tr < 2; ++tr)
#pragma unroll
                for (int tc = 0; tc < 4; ++tc)
                    acc[tr][tc] = __builtin_amdgcn_mfma_f32_16x16x32_bf16(
                        af[tr], bfr[tc], acc[tr][tc], 0, 0, 0);
        }
    }

    // row-norm reduction across the 16 lanes sharing each row group
#pragma unroll
    for (int off = 1; off < 16; off <<= 1) {
#pragma unroll
        for (int it = 0; it < 4; ++it) {
            ssx[it] += __shfl_xor(ssx[it], off);
            ssy[it] += __shfl_xor(ssy[it], off);
        }
    }
    if ((t & 15) == 0) {
#pragma unroll
        for (int it = 0; it < 4; ++it) {
            const int r = r0 + it * 32;
            sinvx[r] = 1.0f / fmaxf(sqrtf(ssx[it]), 1e-5f);
            sinvy[r] = 1.0f / fmaxf(sqrtf(ssy[it]), 1e-5f);
        }
    }
    __syncthreads();

    // epilogue: A = exp(2*cos - 2), masked -> 0
    float* Ab = Aout + (size_t)b * M * NP;
#pragma unroll
    for (int tr = 0; tr < 2; ++tr)
#pragma unroll
        for (int tc = 0; tc < 4; ++tc) {
            const int n = nbase + tc * 16 + col;
            const float ivy_n = sinvy[n];
            const float ymf   = symask[n];
#pragma unroll
            for (int reg = 0; reg < 4; ++reg) {
                const int m = mbase + tr * 16 + quad * 4 + reg;
                const float p = acc[tr][tc][reg] * sinvx[m] * ivy_n;
                const float a = (sxmask[m] + ymf > 0.0f) ? 0.0f : expf(2.0f * p - 2.0f);
                Ab[m * NP + n] = a;
            }
        }
}

// ---------------- K2: 50 IPOT iterations + loss ----------------
// One block per batch, 512 threads. Thread (ti=t>>4, tj=t&15) owns
// rows 4*ti..+3, cols 8*tj..+7 of Q and A (registers).
__launch_bounds__(512, 1)
__global__ void ipot_kernel(const float* __restrict__ Ain,
                            const int* __restrict__ xnum,
                            const int* __restrict__ ynum,
                            float* __restrict__ out)
{
    __shared__ __align__(16) float partCS[8 * 128];
    __shared__ __align__(16) float sdelta[NP];
    __shared__ __align__(16) float ssigma[M];
    __shared__ __align__(16) float sxmask[M];
    __shared__ __align__(16) float symask[NP];
    __shared__ float sxl_s, syl_s;
    __shared__ unsigned scnt[16];
    __shared__ float swsum[8];

    const int b    = blockIdx.x;
    const int t    = threadIdx.x;
    const int lane = t & 63;
    const int w    = t >> 6;
    const int ti   = t >> 4;          // 0..31
    const int tj   = t & 15;          // 0..15
    const int i0   = ti * 4;
    const int j0   = tj * 8;

    bool tpad = true, ipad = true;
    if (t < M)  { tpad = (xnum[b * M + t] == 0); sxmask[t] = tpad ? 1e4f : 0.0f; }
    if (t < NP) { ipad = !(t < NIMG && ynum[b * 128 + t + 1] != 0); symask[t] = ipad ? 1e4f : 0.0f; }
    unsigned long long bx = __ballot(t < M  && !tpad);
    unsigned long long by = __ballot(t < NP && !ipad);
    if (lane == 0) { scnt[w] = (unsigned)__popcll(bx); scnt[8 + w] = (unsigned)__popcll(by); }
    __syncthreads();
    if (t == 0) {
        float xl = 0.f, yl = 0.f;
        for (int k = 0; k < 8; ++k) { xl += scnt[k]; yl += scnt[8 + k]; }
        sxl_s = xl; syl_s = yl;
    }
    __syncthreads();
    const float xl = sxl_s, yl = syl_s;
    if (t < M) ssigma[t] = tpad ? 0.0f : (1.0f / xl);

    // load A (L3-warm from K1); Q0 = A
    const float* Ab = Ain + (size_t)b * M * NP;
    float Af[4][8], Q[4][8];
#pragma unroll
    for (int r = 0; r < 4; ++r) {
        float4 a0 = *(const float4*)(Ab + (size_t)(i0 + r) * NP + j0);
        float4 a1 = *(const float4*)(Ab + (size_t)(i0 + r) * NP + j0 + 4);
        Af[r][0] = a0.x; Af[r][1] = a0.y; Af[r][2] = a0.z; Af[r][3] = a0.w;
        Af[r][4] = a1.x; Af[r][5] = a1.y; Af[r][6] = a1.z; Af[r][7] = a1.w;
#pragma unroll
        for (int j = 0; j < 8; ++j) Q[r][j] = Af[r][j];
    }
    __syncthreads();   // ssigma init visible

    float lp = 0.0f;
    for (int itn = 0; itn < ITERS; ++itn) {
        // ---- colsum[j] = sum_i sigma[i] Q[i][j] ----
        float sg[4];
        *(float4*)sg = *(const float4*)(&ssigma[i0]);
        float cp[8] = {0.f,0.f,0.f,0.f,0.f,0.f,0.f,0.f};
#pragma unroll
        for (int r = 0; r < 4; ++r)
#pragma unroll
            for (int j = 0; j < 8; ++j)
                cp[j] = fmaf(sg[r], Q[r][j], cp[j]);
        // combine the 4 ti-groups living in this wave (lanes xor 16, 32)
#pragma unroll
        for (int j = 0; j < 8; ++j) {
            cp[j] += __shfl_xor(cp[j], 16);
            cp[j] += __shfl_xor(cp[j], 32);
        }
        if (lane < 16) {
            float4 c0 = make_float4(cp[0], cp[1], cp[2], cp[3]);
            float4 c1 = make_float4(cp[4], cp[5], cp[6], cp[7]);
            *(float4*)(&partCS[w * 128 + tj * 8])     = c0;
            *(float4*)(&partCS[w * 128 + tj * 8 + 4]) = c1;
        }
        __syncthreads();
        if (t < NP) {
            float s = 0.f;
#pragma unroll
            for (int w8 = 0; w8 < 8; ++w8) s += partCS[w8 * 128 + t];
            sdelta[t] = 1.0f / (yl * s + symask[t]);
        }
        __syncthreads();
        // ---- rowsum[i] = sum_j delta[j] Q[i][j] ----
        float dl[8];
        *(float4*)dl       = *(const float4*)(&sdelta[j0]);
        *(float4*)(dl + 4) = *(const float4*)(&sdelta[j0 + 4]);
        float rp[4] = {0.f, 0.f, 0.f, 0.f};
#pragma unroll
        for (int r = 0; r < 4; ++r)
#pragma unroll
            for (int j = 0; j < 8; ++j)
                rp[r] = fmaf(dl[j], Q[r][j], rp[r]);
#pragma unroll
        for (int off = 1; off < 16; off <<= 1)
#pragma unroll
            for (int r = 0; r < 4; ++r)
                rp[r] += __shfl_xor(rp[r], off);
        if ((lane & 15) == 0) {
            float4 sv;
            sv.x = 1.0f / (xl * rp[0] + sxmask[i0 + 0]);
            sv.y = 1.0f / (xl * rp[1] + sxmask[i0 + 1]);
            sv.z = 1.0f / (xl * rp[2] + sxmask[i0 + 2]);
            sv.w = 1.0f / (xl * rp[3] + sxmask[i0 + 3]);
            *(float4*)(&ssigma[i0]) = sv;
        }
        __syncthreads();
        float sn[4];
        *(float4*)sn = *(const float4*)(&ssigma[i0]);
        if (itn < ITERS - 1) {
#pragma unroll
            for (int r = 0; r < 4; ++r) {
                const float f = sn[r];
#pragma unroll
                for (int j = 0; j < 8; ++j)
                    Q[r][j] *= Af[r][j] * dl[j] * f;
            }
        } else {
            // loss = sum C * delta[j] * sigma[i] * Q ; C = -0.5 ln A
#pragma unroll
            for (int r = 0; r < 4; ++r)
#pragma unroll
                for (int j = 0; j < 8; ++j) {
                    const float a = Af[r][j];
                    if (a > 0.0f)
                        lp = fmaf(-0.5f * logf(a) * dl[j] * sn[r], Q[r][j], lp);
                }
        }
    }

#pragma unroll
    for (int off = 32; off > 0; off >>= 1) lp += __shfl_down(lp, off);
    if (lane == 0) swsum[w] = lp;
    __syncthreads();
    if (t == 0) {
        float tot = 0.f;
        for (int k = 0; k < 8; ++k) tot += swsum[k];
        atomicAdd(out, 0.01f * tot);
    }
}

extern "C" void kernel_launch(void* const* d_in, const int* in_sizes, int n_in,
                              void* d_out, int out_size, void* d_ws, size_t ws_size,
                              hipStream_t stream) {
    const float* x  = (const float*)d_in[0];
    const float* y  = (const float*)d_in[1];
    const int*   xn = (const int*)d_in[2];
    const int*   yn = (const int*)d_in[3];
    float* out = (float*)d_out;
    float* A   = (float*)d_ws;   // needs 256*128*128*4 = 16.8 MB

    (void)hipMemsetAsync(out, 0, (size_t)out_size * sizeof(float), stream);
    gemm_a_kernel<<<dim3(BATCH), dim3(512), 0, stream>>>(x, y, xn, yn, A);
    ipot_kernel<<<dim3(BATCH), dim3(512), 0, stream>>>(A, xn, yn, out);
}

// Round 4
// 373.941 us; speedup vs baseline: 1.2984x; 1.0302x over previous
//
#include <hip/hip_runtime.h>
#include <math.h>

#define BATCH 256
#define M 128        // txt rows
#define NIMG 127     // valid img cols
#define NP 128       // padded img cols
#define D 1024
#define BK 64        // k-tile
#define NT (D / BK)  // 16 k-tiles
#define ITERS 50
#define LROW 72      // LDS row stride in bf16 elems (64 + 8 pad)

typedef __attribute__((ext_vector_type(8))) short bf16x8;
typedef __attribute__((ext_vector_type(4))) float floatx4;

// pack two floats to bf16x2 (RNE), bit-level
static __device__ __forceinline__ unsigned pack_bf16x2(float a, float b) {
    unsigned ua = __builtin_bit_cast(unsigned, a);
    unsigned ub = __builtin_bit_cast(unsigned, b);
    ua += 0x7fffu + ((ua >> 16) & 1u);
    ub += 0x7fffu + ((ub >> 16) & 1u);
    return (ua >> 16) | (ub & 0xffff0000u);
}

// DPP row_ror:n add (16-lane rotate) — VALU-pipe reduction, no DS ops
template<int CTRL>
static __device__ __forceinline__ float dpp_add(float v) {
    int s = __builtin_amdgcn_update_dpp(0, __builtin_bit_cast(int, v), CTRL, 0xf, 0xf, true);
    return v + __builtin_bit_cast(float, s);
}
// full 16-lane (DPP row) sum, result in all 16 lanes
static __device__ __forceinline__ float red16(float v) {
    v = dpp_add<0x121>(v);   // row_ror:1
    v = dpp_add<0x122>(v);   // row_ror:2
    v = dpp_add<0x124>(v);   // row_ror:4
    v = dpp_add<0x128>(v);   // row_ror:8
    return v;
}

// ---------------- K1 helpers ----------------
static __device__ __forceinline__ void load_tile(const float* __restrict__ xb,
                                                 const float* __restrict__ yb,
                                                 int kk, int r0, int c16,
                                                 float4 (&vx)[4], float4 (&vy)[4]) {
#pragma unroll
    for (int it = 0; it < 4; ++it) {
        const int r = r0 + it * 32;
        vx[it] = *(const float4*)(xb + (size_t)r * D + kk + c16 * 4);
        float4 z = make_float4(0.f, 0.f, 0.f, 0.f);
        if (r < NIMG) z = *(const float4*)(yb + (size_t)r * D + kk + c16 * 4);
        vy[it] = z;
    }
}

static __device__ __forceinline__ void stage_tile(short* __restrict__ Xs, short* __restrict__ Ys,
                                                  int r0, int c16,
                                                  const float4 (&vx)[4], const float4 (&vy)[4],
                                                  float (&ssx)[4], float (&ssy)[4]) {
#pragma unroll
    for (int it = 0; it < 4; ++it) {
        const int r = r0 + it * 32;
        float4 v = vx[it];
        ssx[it] = fmaf(v.x, v.x, fmaf(v.y, v.y, fmaf(v.z, v.z, fmaf(v.w, v.w, ssx[it]))));
        uint2 p;
        p.x = pack_bf16x2(v.x, v.y);
        p.y = pack_bf16x2(v.z, v.w);
        *(uint2*)(&Xs[r * LROW + c16 * 4]) = p;
        v = vy[it];
        ssy[it] = fmaf(v.x, v.x, fmaf(v.y, v.y, fmaf(v.z, v.z, fmaf(v.w, v.w, ssy[it]))));
        p.x = pack_bf16x2(v.x, v.y);
        p.y = pack_bf16x2(v.z, v.w);
        *(uint2*)(&Ys[r * LROW + c16 * 4]) = p;
    }
}

static __device__ __forceinline__ void mfma_tile(const short* __restrict__ Xs,
                                                 const short* __restrict__ Ys,
                                                 int mbase, int nbase, int col, int quad,
                                                 floatx4 (&acc)[2][4]) {
#pragma unroll
    for (int ks = 0; ks < 2; ++ks) {
        const int koff = ks * 32 + quad * 8;
        bf16x8 af[2], bfr[4];
#pragma unroll
        for (int tr = 0; tr < 2; ++tr)
            af[tr] = *(const bf16x8*)(&Xs[(mbase + tr * 16 + col) * LROW + koff]);
#pragma unroll
        for (int tc = 0; tc < 4; ++tc)
            bfr[tc] = *(const bf16x8*)(&Ys[(nbase + tc * 16 + col) * LROW + koff]);
#pragma unroll
        for (int tr = 0; tr < 2; ++tr)
#pragma unroll
            for (int tc = 0; tc < 4; ++tc)
                acc[tr][tc] = __builtin_amdgcn_mfma_f32_16x16x32_bf16(
                    af[tr], bfr[tc], acc[tr][tc], 0, 0, 0);
    }
}

// ---------------- K1: cosine-cost GEMM -> A = exp(-2C) masked ----------------
__launch_bounds__(512, 1)
__global__ void gemm_a_kernel(const float* __restrict__ xg,
                              const float* __restrict__ yg,
                              const int* __restrict__ xnum,
                              const int* __restrict__ ynum,
                              float* __restrict__ Aout)
{
    __shared__ __align__(16) short Xs[M * LROW];
    __shared__ __align__(16) short Ys[M * LROW];
    __shared__ __align__(16) float sinvx[M];
    __shared__ __align__(16) float sinvy[NP];
    __shared__ __align__(16) float sxmask[M];
    __shared__ __align__(16) float symask[NP];

    const int b    = blockIdx.x;
    const int t    = threadIdx.x;
    const int lane = t & 63;
    const int w    = t >> 6;

    const float* xb = xg + (size_t)b * M * D;
    const float* yb = yg + ((size_t)b * 128 + 1) * D;

    if (t < M)  sxmask[t] = (xnum[b * M + t] == 0) ? 1.0f : 0.0f;
    if (t < NP) symask[t] = (t < NIMG && ynum[b * 128 + t + 1] != 0) ? 0.0f : 1.0f;

    const int r0  = t >> 4;
    const int c16 = t & 15;

    floatx4 acc[2][4];
#pragma unroll
    for (int a = 0; a < 2; ++a)
#pragma unroll
        for (int c = 0; c < 4; ++c) acc[a][c] = (floatx4)0.0f;

    float ssx[4] = {0.f, 0.f, 0.f, 0.f};
    float ssy[4] = {0.f, 0.f, 0.f, 0.f};

    const int mbase = (w & 3) * 32;
    const int nbase = (w >> 2) * 64;
    const int col   = lane & 15;
    const int quad  = lane >> 4;

    // software-pipelined K loop: two named register buffers (stay in VGPRs)
    float4 vxa[4], vya[4], vxb[4], vyb[4];
    load_tile(xb, yb, 0, r0, c16, vxa, vya);

#pragma unroll 1
    for (int ii = 0; ii < NT; ii += 2) {
        // even tile: consume A, prefetch into B
        stage_tile(Xs, Ys, r0, c16, vxa, vya, ssx, ssy);
        load_tile(xb, yb, (ii + 1) * BK, r0, c16, vxb, vyb);   // ii+1 <= 15 always
        __syncthreads();
        mfma_tile(Xs, Ys, mbase, nbase, col, quad, acc);
        __syncthreads();
        // odd tile: consume B, prefetch into A
        stage_tile(Xs, Ys, r0, c16, vxb, vyb, ssx, ssy);
        if (ii + 2 < NT) load_tile(xb, yb, (ii + 2) * BK, r0, c16, vxa, vya);
        __syncthreads();
        mfma_tile(Xs, Ys, mbase, nbase, col, quad, acc);
        __syncthreads();
    }

    // row-norm reduction across the 16 lanes (c16) sharing each row — DPP
#pragma unroll
    for (int it = 0; it < 4; ++it) {
        ssx[it] = red16(ssx[it]);
        ssy[it] = red16(ssy[it]);
    }
    if (c16 == 0) {
#pragma unroll
        for (int it = 0; it < 4; ++it) {
            const int r = r0 + it * 32;
            sinvx[r] = 1.0f / fmaxf(sqrtf(ssx[it]), 1e-5f);
            sinvy[r] = 1.0f / fmaxf(sqrtf(ssy[it]), 1e-5f);
        }
    }
    __syncthreads();

    // epilogue: A = exp(2*cos - 2), masked -> 0
    float* Ab = Aout + (size_t)b * M * NP;
#pragma unroll
    for (int tr = 0; tr < 2; ++tr)
#pragma unroll
        for (int tc = 0; tc < 4; ++tc) {
            const int n = nbase + tc * 16 + col;
            const float ivy_n = sinvy[n];
            const float ymf   = symask[n];
#pragma unroll
            for (int reg = 0; reg < 4; ++reg) {
                const int m = mbase + tr * 16 + quad * 4 + reg;
                const float p = acc[tr][tc][reg] * sinvx[m] * ivy_n;
                const float a = (sxmask[m] + ymf > 0.0f) ? 0.0f : expf(2.0f * p - 2.0f);
                Ab[m * NP + n] = a;
            }
        }
}

// ---------------- K2: 50 IPOT iterations + loss ----------------
__launch_bounds__(512, 1)
__global__ void ipot_kernel(const float* __restrict__ Ain,
                            const int* __restrict__ xnum,
                            const int* __restrict__ ynum,
                            float* __restrict__ out)
{
    __shared__ __align__(16) float partCS[8 * 128];
    __shared__ __align__(16) float sdelta[NP];
    __shared__ __align__(16) float ssigma[M];
    __shared__ __align__(16) float sxmask[M];
    __shared__ __align__(16) float symask[NP];
    __shared__ float sxl_s, syl_s;
    __shared__ unsigned scnt[16];
    __shared__ float swsum[8];

    const int b    = blockIdx.x;
    const int t    = threadIdx.x;
    const int lane = t & 63;
    const int w    = t >> 6;
    const int tj   = t & 15;
    const int i0   = (t >> 4) * 4;
    const int j0   = tj * 8;

    bool tpad = true, ipad = true;
    if (t < M)  { tpad = (xnum[b * M + t] == 0); sxmask[t] = tpad ? 1e4f : 0.0f; }
    if (t < NP) { ipad = !(t < NIMG && ynum[b * 128 + t + 1] != 0); symask[t] = ipad ? 1e4f : 0.0f; }
    unsigned long long bx = __ballot(t < M  && !tpad);
    unsigned long long by = __ballot(t < NP && !ipad);
    if (lane == 0) { scnt[w] = (unsigned)__popcll(bx); scnt[8 + w] = (unsigned)__popcll(by); }
    __syncthreads();
    if (t == 0) {
        float xl = 0.f, yl = 0.f;
        for (int k = 0; k < 8; ++k) { xl += scnt[k]; yl += scnt[8 + k]; }
        sxl_s = xl; syl_s = yl;
    }
    __syncthreads();
    const float xl = sxl_s, yl = syl_s;
    if (t < M) ssigma[t] = tpad ? 0.0f : __builtin_amdgcn_rcpf(xl);

    const float* Ab = Ain + (size_t)b * M * NP;
    float Af[4][8], Q[4][8];
#pragma unroll
    for (int r = 0; r < 4; ++r) {
        float4 a0 = *(const float4*)(Ab + (size_t)(i0 + r) * NP + j0);
        float4 a1 = *(const float4*)(Ab + (size_t)(i0 + r) * NP + j0 + 4);
        Af[r][0] = a0.x; Af[r][1] = a0.y; Af[r][2] = a0.z; Af[r][3] = a0.w;
        Af[r][4] = a1.x; Af[r][5] = a1.y; Af[r][6] = a1.z; Af[r][7] = a1.w;
#pragma unroll
        for (int j = 0; j < 8; ++j) Q[r][j] = Af[r][j];
    }
    __syncthreads();

    float lp = 0.0f;
    for (int itn = 0; itn < ITERS; ++itn) {
        // ---- colsum[j] = sum_i sigma[i] Q[i][j] ----
        float sg[4];
        *(float4*)sg = *(const float4*)(&ssigma[i0]);
        float cp[8] = {0.f,0.f,0.f,0.f,0.f,0.f,0.f,0.f};
#pragma unroll
        for (int r = 0; r < 4; ++r)
#pragma unroll
            for (int j = 0; j < 8; ++j)
                cp[j] = fmaf(sg[r], Q[r][j], cp[j]);
#pragma unroll
        for (int j = 0; j < 8; ++j) {
            cp[j] += __shfl_xor(cp[j], 16);
            cp[j] += __shfl_xor(cp[j], 32);
        }
        if (lane < 16) {
            float4 c0 = make_float4(cp[0], cp[1], cp[2], cp[3]);
            float4 c1 = make_float4(cp[4], cp[5], cp[6], cp[7]);
            *(float4*)(&partCS[w * 128 + tj * 8])     = c0;
            *(float4*)(&partCS[w * 128 + tj * 8 + 4]) = c1;
        }
        __syncthreads();
        if (t < NP) {
            float s = 0.f;
#pragma unroll
            for (int w8 = 0; w8 < 8; ++w8) s += partCS[w8 * 128 + t];
            sdelta[t] = __builtin_amdgcn_rcpf(yl * s + symask[t]);
        }
        __syncthreads();
        // ---- rowsum[i] = sum_j delta[j] Q[i][j] ----
        float dl[8];
        *(float4*)dl       = *(const float4*)(&sdelta[j0]);
        *(float4*)(dl + 4) = *(const float4*)(&sdelta[j0 + 4]);
        float rp[4] = {0.f, 0.f, 0.f, 0.f};
#pragma unroll
        for (int r = 0; r < 4; ++r)
#pragma unroll
            for (int j = 0; j < 8; ++j)
                rp[r] = fmaf(dl[j], Q[r][j], rp[r]);
        // 16-lane reduce on the VALU pipe (DPP), not DS
#pragma unroll
        for (int r = 0; r < 4; ++r) rp[r] = red16(rp[r]);
        if ((lane & 15) == 0) {
            float4 sv;
            sv.x = __builtin_amdgcn_rcpf(xl * rp[0] + sxmask[i0 + 0]);
            sv.y = __builtin_amdgcn_rcpf(xl * rp[1] + sxmask[i0 + 1]);
            sv.z = __builtin_amdgcn_rcpf(xl * rp[2] + sxmask[i0 + 2]);
            sv.w = __builtin_amdgcn_rcpf(xl * rp[3] + sxmask[i0 + 3]);
            *(float4*)(&ssigma[i0]) = sv;
        }
        __syncthreads();
        float sn[4];
        *(float4*)sn = *(const float4*)(&ssigma[i0]);
        if (itn < ITERS - 1) {
#pragma unroll
            for (int r = 0; r < 4; ++r) {
                const float f = sn[r];
#pragma unroll
                for (int j = 0; j < 8; ++j)
                    Q[r][j] *= Af[r][j] * dl[j] * f;
            }
        } else {
#pragma unroll
            for (int r = 0; r < 4; ++r)
#pragma unroll
                for (int j = 0; j < 8; ++j) {
                    const float a = Af[r][j];
                    if (a > 0.0f)
                        lp = fmaf(-0.5f * logf(a) * dl[j] * sn[r], Q[r][j], lp);
                }
        }
    }

#pragma unroll
    for (int off = 32; off > 0; off >>= 1) lp += __shfl_down(lp, off);
    if (lane == 0) swsum[w] = lp;
    __syncthreads();
    if (t == 0) {
        float tot = 0.f;
        for (int k = 0; k < 8; ++k) tot += swsum[k];
        atomicAdd(out, 0.01f * tot);
    }
}

extern "C" void kernel_launch(void* const* d_in, const int* in_sizes, int n_in,
                              void* d_out, int out_size, void* d_ws, size_t ws_size,
                              hipStream_t stream) {
    const float* x  = (const float*)d_in[0];
    const float* y  = (const float*)d_in[1];
    const int*   xn = (const int*)d_in[2];
    const int*   yn = (const int*)d_in[3];
    float* out = (float*)d_out;
    float* A   = (float*)d_ws;   // 256*128*128*4 = 16.8 MB

    (void)hipMemsetAsync(out, 0, (size_t)out_size * sizeof(float), stream);
    gemm_a_kernel<<<dim3(BATCH), dim3(512), 0, stream>>>(x, y, xn, yn, A);
    ipot_kernel<<<dim3(BATCH), dim3(512), 0, stream>>>(A, xn, yn, out);
}